// Round 4
// baseline (175.876 us; speedup 1.0000x reference)
//
#include <hip/hip_runtime.h>

// RandomForest: 131072 samples x 64 feat, 64 trees depth 12, 8-class vote.
//
// R13 = R12 resubmitted (container failed twice = infra flake; no counter
// evidence against the design). Theory recap: R9's walk is L2-request-bound
// (~15.7M scattered 64B line-requests, model 51us ~= measured 47.8us).
// Tables are 21.5KB/tree < 32KB L1, but R9 kept 8 tree streams live per CU
// -> L1 thrash. This structure: 1 block/CU (TPB=512, SPB=512, X tile 128KB
// LDS -- 128KB/workgroup is proven on gfx950 by the m201 GEMM template),
// 1 thread per sample walking ALL 64 trees sequentially, __syncthreads()
// per tree so the CU's 8 waves share one L1-resident table, plus a 342-line
// prefetch of tree t+1 during tree t. Votes are thread-local (no h-split /
// vbuf reduction). Two launches total (fused pack + walk).

constexpr int kSamples  = 131072;
constexpr int kFeat     = 64;
constexpr int kTrees    = 64;
constexpr int kInternal = 4095;
constexpr int kClasses  = 8;

constexpr int TPB = 512;
constexpr int SPB = 512;                          // samples per block
constexpr int XLDS_BYTES = kFeat * SPB * 4;       // 131072 B = 128 KiB

// Pair p covers levels 2p,2p+1; entries-before offsets {0,1,5,21,85}, 341/tree,
// stride 512 -> tree base = t<<9.
struct Pair  { float thr0, thrL, thrR; unsigned meta; };  // meta: f0|fL<<6|fR<<12
struct Sub16 { float thr10, thrL, thrR; unsigned meta; }; // +lv0..lv3 <<18,21,24,27

constexpr int kPairItems = kTrees * 341;              // 21824
constexpr int kSubItems  = kTrees * 1024;             // 65536
constexpr int kPackItems = kPairItems + kSubItems;    // 87360

// ---------------- fused pack kernel (one launch) ----------------

__global__ __launch_bounds__(256) void pack_kernel(
    const int* __restrict__ features, const float* __restrict__ thresholds,
    const int* __restrict__ leaf_values,
    Pair* __restrict__ pairsA, Sub16* __restrict__ subsA)
{
    int g = blockIdx.x * 256 + threadIdx.x;
    if (g < kPairItems) {
        int t = g / 341;
        int e = g - t * 341;
        int p, m;
        if      (e < 1)  { p = 0; m = e; }
        else if (e < 5)  { p = 1; m = e - 1; }
        else if (e < 21) { p = 2; m = e - 5; }
        else if (e < 85) { p = 3; m = e - 21; }
        else             { p = 4; m = e - 85; }
        int g0 = (1 << (2 * p)) - 1 + m;              // global node id at level 2p
        int b  = t * kInternal;
        Pair pr;
        pr.thr0 = thresholds[b + g0];
        pr.thrL = thresholds[b + 2 * g0 + 1];
        pr.thrR = thresholds[b + 2 * g0 + 2];
        pr.meta = (unsigned)features[b + g0]
                | ((unsigned)features[b + 2 * g0 + 1] << 6)
                | ((unsigned)features[b + 2 * g0 + 2] << 12);
        pairsA[(t << 9) + e] = pr;
    } else if (g < kPackItems) {
        int i2 = g - kPairItems;
        int t = i2 >> 10;
        int j = i2 & 1023;                             // level-10 local index
        int n10 = 1023 + j;
        int b   = t * kInternal;
        Sub16 sb;
        sb.thr10 = thresholds[b + n10];
        sb.thrL  = thresholds[b + 2 * n10 + 1];
        sb.thrR  = thresholds[b + 2 * n10 + 2];
        const int* lv = leaf_values + ((t << 12) + 4 * j);
        sb.meta = (unsigned)features[b + n10]
                | ((unsigned)features[b + 2 * n10 + 1] << 6)
                | ((unsigned)features[b + 2 * n10 + 2] << 12)
                | ((unsigned)lv[0] << 18) | ((unsigned)lv[1] << 21)
                | ((unsigned)lv[2] << 24) | ((unsigned)lv[3] << 27);
        subsA[(t << 10) + j] = sb;
    }
}

// ---------------- walk kernel: one tree at a time per CU ----------------

// Prefetch tree t's tables toward L1: pairs 341*16B = 86 lines, subs 16KB =
// 256 lines -> 342 lines, one 64B line per thread s<342. Loads kept live via
// empty asm (guide rule #17); they retire while the previous tree computes.
__device__ __forceinline__ void prefetch_tree(
    const Pair* pairsA, const Sub16* subsA, int t, int s)
{
    if (s < 342) {
        const char* pf = (s < 86)
            ? ((const char*)pairsA + (t << 13) + (s << 6))
            : ((const char*)subsA  + (t << 14) + ((s - 86) << 6));
        unsigned pv = *(const unsigned*)pf;
        asm volatile("" :: "v"(pv));
    }
}

__global__ __launch_bounds__(TPB, 2) void forest_kernel(
    const float* __restrict__ X,
    const Pair*  __restrict__ pairsA,   // [64][512] (341 used)
    const Sub16* __restrict__ subsA,    // [64][1024]
    int* __restrict__ out)
{
    extern __shared__ float xs[];                  // [64][512] feature-major
    const int s    = threadIdx.x;                  // sample slot 0..511
    const int base = blockIdx.x * SPB;

    // Stage: each thread loads its own sample row (16 float4). Lane addresses
    // are 256B-strided; the 4 consecutive k's share each 64B line (L1 absorbs).
    {
        const float4* Xr = (const float4*)(X + (size_t)(base + s) * kFeat);
        #pragma unroll
        for (int k = 0; k < 16; ++k) {
            float4 v = Xr[k];
            int f0 = k * 4;
            xs[(f0 + 0) * SPB + s] = v.x;
            xs[(f0 + 1) * SPB + s] = v.y;
            xs[(f0 + 2) * SPB + s] = v.z;
            xs[(f0 + 3) * SPB + s] = v.w;
        }
    }
    // Warm L1 with tree 0's tables while staging loads are in flight.
    prefetch_tree(pairsA, subsA, 0, s);
    __syncthreads();

    // LDS banking: addr/4 % 32 = (f*512 + s) % 32 = s % 32 for ANY f ->
    // a wave's 64 lanes always map 2 lanes/bank regardless of divergent f
    // (2-way aliasing is free, m136).
    const char* xb = (const char*)xs + (s << 2);   // + (f<<11) per access
    unsigned long long votes = 0ull;

    const int mofs[5] = {0, 1, 5, 21, 85};         // pair-level entry offsets

    for (int t = 0; t < kTrees; ++t) {
        // Overlap: pull tree t+1's 342 lines toward L1 during tree t's walk.
        if (t + 1 < kTrees) prefetch_tree(pairsA, subsA, t + 1, s);

        int m = 0;
        #pragma unroll
        for (int p = 0; p < 5; ++p) {              // levels 0..9, two per step
            Pair pr = pairsA[(t << 9) + mofs[p] + m];
            float x0 = *(const float*)(xb + ((pr.meta & 63u) << 11));
            int c0 = x0 > pr.thr0 ? 1 : 0;
            float thr1     = c0 ? pr.thrR : pr.thrL;
            unsigned fsel  = c0 ? (pr.meta >> 12) : (pr.meta >> 6);
            float x1 = *(const float*)(xb + ((fsel & 63u) << 11));
            int c1 = x1 > thr1 ? 1 : 0;
            m = 4 * m + 2 * c0 + c1;
        }

        {                                          // levels 10,11 + leaf
            Sub16 sb = subsA[(t << 10) + m];
            unsigned mt = sb.meta;
            float x0 = *(const float*)(xb + ((mt & 63u) << 11));
            int c0 = x0 > sb.thr10 ? 1 : 0;
            float thr1    = c0 ? sb.thrR : sb.thrL;
            unsigned fsel = c0 ? (mt >> 12) : (mt >> 6);
            float x1 = *(const float*)(xb + ((fsel & 63u) << 11));
            int c1 = x1 > thr1 ? 1 : 0;
            int cls = (mt >> (18 + 3 * ((c0 << 1) | c1))) & 7;
            votes += 1ull << (cls << 3);
        }

        // Keep the CU's 8 waves on the same tree so its 21.5KB table stays
        // L1-resident (the whole point of this structure).
        __syncthreads();
    }

    // Thread-local argmax over 8 packed byte counters; strict '>' keeps the
    // smallest class on ties (torch.mode convention).
    int best = 0;
    int bc   = (int)(votes & 0xFFull);
    #pragma unroll
    for (int c = 1; c < kClasses; ++c) {
        int cnt = (int)((votes >> (c * 8)) & 0xFFull);
        if (cnt > bc) { bc = cnt; best = c; }
    }
    out[base + s] = best;
}

extern "C" void kernel_launch(void* const* d_in, const int* in_sizes, int n_in,
                              void* d_out, int out_size, void* d_ws, size_t ws_size,
                              hipStream_t stream) {
    const float* X          = (const float*)d_in[0];
    const int*   features   = (const int*)d_in[1];
    const float* thresholds = (const float*)d_in[2];
    const int*   leaves     = (const int*)d_in[3];
    int*         out        = (int*)d_out;

    Pair*  pairsA = (Pair*)d_ws;                            // 64*512*16 = 512 KiB
    Sub16* subsA  = (Sub16*)((char*)d_ws + (kTrees << 13)); // +512 KiB, 1 MiB

    (void)hipFuncSetAttribute((const void*)forest_kernel,
                              hipFuncAttributeMaxDynamicSharedMemorySize,
                              XLDS_BYTES);

    pack_kernel<<<(kPackItems + 255) / 256, 256, 0, stream>>>(
        features, thresholds, leaves, pairsA, subsA);
    forest_kernel<<<kSamples / SPB, TPB, XLDS_BYTES, stream>>>(
        X, pairsA, subsA, out);
}

// Round 5
// 116.813 us; speedup vs baseline: 1.5056x; 1.5056x over previous
//
#include <hip/hip_runtime.h>

// RandomForest: 131072 samples x 64 feat, 64 trees depth 12, 8-class vote.
//
// R14 = recovery to the proven optimum. R13 post-mortem: one-tree-at-a-time
// killed chain parallelism (2 concurrent chains/SIMD vs R9's 64) -> walk
// 108us despite L1-resident tables; VALU busy-TIME identical (~22us) in
// both -> pure latency exposure. L1-residency (needs <=1.5 trees/CU active)
// and chain-ILP (needs >=4-8 live trees) are structurally incompatible under
// the 128KB LDS X-tile cap. R9's walk is at the L2 scattered-request
// saturation point (15.7M 64B lines / 8 XCD / 47.8us ~= 17 req/cyc/XCD):
// restore it verbatim. Only change vs R9: the two pack kernels are fused
// into one launch (identical math, branch on item index) -> 2 launches.
//
// Walk structure (R9, measured 47.8us steady): 256 samples/block in a
// 64KB feature-major LDS tile, TPB=1024, 4 threads/sample (16 trees each =
// 2 ILP-8 windows), grid=512 -> 2 blocks/CU -> 32 waves/CU.

constexpr int kSamples  = 131072;
constexpr int kFeat     = 64;
constexpr int kTrees    = 64;
constexpr int kInternal = 4095;
constexpr int kClasses  = 8;

constexpr int TPB  = 1024;
constexpr int SPB  = 256;                        // samples per block
constexpr int XSTR = 256;                        // dwords; f column = f<<10 bytes
constexpr int XLDS_BYTES = kFeat * XSTR * 4;     // 65536 B
constexpr int ILP  = 8;
constexpr int TREES_PER_THREAD = 16;             // 4 thread-slices per sample

// Pair p covers levels 2p,2p+1; entries-before offsets {0,1,5,21,85}, 341/tree,
// stride 512 -> tree base = t<<9.
struct Pair  { float thr0, thrL, thrR; unsigned meta; };  // meta: f0|fL<<6|fR<<12
struct Sub16 { float thr10, thrL, thrR; unsigned meta; }; // +lv0..lv3 <<18,21,24,27

constexpr int kPairItems = kTrees * 341;              // 21824
constexpr int kSubItems  = kTrees * 1024;             // 65536
constexpr int kPackItems = kPairItems + kSubItems;    // 87360

// ---------------- fused pack kernel (one launch) ----------------

__global__ __launch_bounds__(256) void pack_kernel(
    const int* __restrict__ features, const float* __restrict__ thresholds,
    const int* __restrict__ leaf_values,
    Pair* __restrict__ pairsA, Sub16* __restrict__ subsA)
{
    int g = blockIdx.x * 256 + threadIdx.x;
    if (g < kPairItems) {
        int t = g / 341;
        int e = g - t * 341;
        int p, m;
        if      (e < 1)  { p = 0; m = e; }
        else if (e < 5)  { p = 1; m = e - 1; }
        else if (e < 21) { p = 2; m = e - 5; }
        else if (e < 85) { p = 3; m = e - 21; }
        else             { p = 4; m = e - 85; }
        int g0 = (1 << (2 * p)) - 1 + m;              // global node id at level 2p
        int b  = t * kInternal;
        Pair pr;
        pr.thr0 = thresholds[b + g0];
        pr.thrL = thresholds[b + 2 * g0 + 1];
        pr.thrR = thresholds[b + 2 * g0 + 2];
        pr.meta = (unsigned)features[b + g0]
                | ((unsigned)features[b + 2 * g0 + 1] << 6)
                | ((unsigned)features[b + 2 * g0 + 2] << 12);
        pairsA[(t << 9) + e] = pr;
    } else if (g < kPackItems) {
        int i2 = g - kPairItems;
        int t = i2 >> 10;
        int j = i2 & 1023;                             // level-10 local index
        int n10 = 1023 + j;
        int b   = t * kInternal;
        Sub16 sb;
        sb.thr10 = thresholds[b + n10];
        sb.thrL  = thresholds[b + 2 * n10 + 1];
        sb.thrR  = thresholds[b + 2 * n10 + 2];
        const int* lv = leaf_values + ((t << 12) + 4 * j);
        sb.meta = (unsigned)features[b + n10]
                | ((unsigned)features[b + 2 * n10 + 1] << 6)
                | ((unsigned)features[b + 2 * n10 + 2] << 12)
                | ((unsigned)lv[0] << 18) | ((unsigned)lv[1] << 21)
                | ((unsigned)lv[2] << 24) | ((unsigned)lv[3] << 27);
        subsA[(t << 10) + j] = sb;
    }
}

// ---------------- walk kernel (R9 verbatim) ----------------

__global__ __launch_bounds__(TPB, 8) void forest_kernel(
    const float* __restrict__ X,
    const Pair*  __restrict__ pairsA,   // [64][512] (341 used)
    const Sub16* __restrict__ subsA,    // [64][1024]
    int* __restrict__ out)
{
    extern __shared__ float xs[];                  // [64][256] feature-major
    const int tid  = threadIdx.x;
    const int s    = tid & (SPB - 1);              // sample slot 0..255
    const int h    = tid >> 8;                     // forest quarter 0..3
    const int base = blockIdx.x * SPB;

    // Stage: 4 threads per sample each load a quarter-row (4 float4).
    // LDS writes at f*256+s -> bank = s%32, consecutive lanes = 2-way (free).
    {
        const float4* Xr = (const float4*)(X + (size_t)(base + s) * kFeat) + h * 4;
        #pragma unroll
        for (int k = 0; k < 4; ++k) {
            float4 v = Xr[k];
            int f0 = (h * 4 + k) * 4;
            xs[(f0 + 0) * XSTR + s] = v.x;
            xs[(f0 + 1) * XSTR + s] = v.y;
            xs[(f0 + 2) * XSTR + s] = v.z;
            xs[(f0 + 3) * XSTR + s] = v.w;
        }
    }
    __syncthreads();

    const char* xb = (const char*)xs + (s << 2);   // + (f<<10) per access
    unsigned long long votes = 0ull;

    const int mofs[4] = {0, 1, 5, 21};             // shallow pair offsets

    const int tbeg = h * TREES_PER_THREAD;
    for (int t0 = tbeg; t0 < tbeg + TREES_PER_THREAD; t0 += ILP) {
        int m[ILP];
        #pragma unroll
        for (int j = 0; j < ILP; ++j) m[j] = 0;

        #pragma unroll
        for (int p = 0; p < 4; ++p) {              // levels 0..7
            #pragma unroll
            for (int j = 0; j < ILP; ++j) {        // 8 independent chains
                Pair pr = pairsA[((t0 + j) << 9) + mofs[p] + m[j]];
                float x0 = *(const float*)(xb + ((pr.meta & 63u) << 10));
                int c0 = x0 > pr.thr0 ? 1 : 0;
                float thr1     = c0 ? pr.thrR : pr.thrL;
                unsigned fsel  = c0 ? (pr.meta >> 12) : (pr.meta >> 6);
                float x1 = *(const float*)(xb + ((fsel & 63u) << 10));
                int c1 = x1 > thr1 ? 1 : 0;
                m[j] = 4 * m[j] + 2 * c0 + c1;
            }
        }

        #pragma unroll
        for (int j = 0; j < ILP; ++j) {            // levels 8,9 (pair4)
            Pair pr = pairsA[((t0 + j) << 9) + 85 + m[j]];
            float x0 = *(const float*)(xb + ((pr.meta & 63u) << 10));
            int c0 = x0 > pr.thr0 ? 1 : 0;
            float thr1     = c0 ? pr.thrR : pr.thrL;
            unsigned fsel  = c0 ? (pr.meta >> 12) : (pr.meta >> 6);
            float x1 = *(const float*)(xb + ((fsel & 63u) << 10));
            int c1 = x1 > thr1 ? 1 : 0;
            m[j] = 4 * m[j] + 2 * c0 + c1;
        }

        #pragma unroll
        for (int j = 0; j < ILP; ++j) {            // levels 10,11 + leaf
            Sub16 sb = subsA[((t0 + j) << 10) + m[j]];
            unsigned mt = sb.meta;
            float x0 = *(const float*)(xb + ((mt & 63u) << 10));
            int c0 = x0 > sb.thr10 ? 1 : 0;
            float thr1    = c0 ? sb.thrR : sb.thrL;
            unsigned fsel = c0 ? (mt >> 12) : (mt >> 6);
            float x1 = *(const float*)(xb + ((fsel & 63u) << 10));
            int c1 = x1 > thr1 ? 1 : 0;
            int cls = (mt >> (18 + 3 * ((c0 << 1) | c1))) & 7;
            votes += 1ull << (cls << 3);
        }
    }

    // Combine 4 partial vote vectors per sample through LDS (xs dead now).
    __syncthreads();
    unsigned long long* vbuf = (unsigned long long*)xs;   // 3*256 u64 = 6 KiB
    if (h != 0) vbuf[(h - 1) * SPB + s] = votes;
    __syncthreads();
    if (h == 0) {
        votes += vbuf[s] + vbuf[SPB + s] + vbuf[2 * SPB + s];
        // argmax over 8 packed byte counters; strict '>' keeps smallest class
        int best = 0;
        int bc   = (int)(votes & 0xFFull);
        #pragma unroll
        for (int c = 1; c < kClasses; ++c) {
            int cnt = (int)((votes >> (c * 8)) & 0xFFull);
            if (cnt > bc) { bc = cnt; best = c; }
        }
        out[base + s] = best;
    }
}

extern "C" void kernel_launch(void* const* d_in, const int* in_sizes, int n_in,
                              void* d_out, int out_size, void* d_ws, size_t ws_size,
                              hipStream_t stream) {
    const float* X          = (const float*)d_in[0];
    const int*   features   = (const int*)d_in[1];
    const float* thresholds = (const float*)d_in[2];
    const int*   leaves     = (const int*)d_in[3];
    int*         out        = (int*)d_out;

    Pair*  pairsA = (Pair*)d_ws;                            // 64*512*16 = 512 KiB
    Sub16* subsA  = (Sub16*)((char*)d_ws + (kTrees << 13)); // +512 KiB, 1 MiB

    (void)hipFuncSetAttribute((const void*)forest_kernel,
                              hipFuncAttributeMaxDynamicSharedMemorySize,
                              XLDS_BYTES);

    pack_kernel<<<(kPackItems + 255) / 256, 256, 0, stream>>>(
        features, thresholds, leaves, pairsA, subsA);
    forest_kernel<<<kSamples / SPB, TPB, XLDS_BYTES, stream>>>(
        X, pairsA, subsA, out);
}